// Round 9
// baseline (399.108 us; speedup 1.0000x reference)
//
#include <hip/hip_runtime.h>
#include <math.h>

typedef __attribute__((ext_vector_type(8))) short short8;
typedef __attribute__((ext_vector_type(4))) float f32x4;

#define INF 3.0e38f
#define BN_EPS 1e-5f

__device__ __forceinline__ unsigned short f2bf(float x) {
    union { float f; unsigned u; } v; v.f = x;
    unsigned r = v.u + 0x7FFF + ((v.u >> 16) & 1);   // RNE
    return (unsigned short)(r >> 16);
}

// ---------------------------------------------------------------- 3-NN ----
// Scalar-pipe scan (SMEM loads, no LDS staging). Two-pass: pass 1 = top-3
// values (5-op min/max net, ~11 instr/cand); merge -> thr; pass 2 = rescan
// with 8-wide screen (min8 <= thr fires ~35% of wave-steps), rare u64
// (f32bits<<32|idx) lex insert. Selection == lax.top_k semantics, bit-exact.
__global__ __launch_bounds__(256) void knn3_kernel(
    const float* __restrict__ unk, const float* __restrict__ kn,
    const int* __restrict__ ucnt, const int* __restrict__ kcnt,
    int B, int N, float* __restrict__ wgt, int* __restrict__ idxo)
{
    __shared__ float md[4][64][3];
    __shared__ float d2g[64];
    __shared__ unsigned long long mk[4][64][3];

    int tid = threadIdx.x;
    int s = __builtin_amdgcn_readfirstlane(tid >> 6);   // wave id, pinned SGPR
    int lane = tid & 63;
    int pbase = blockIdx.x * 64;
    int p = pbase + lane;

    int cum = 0, bb = 0;
    for (int i = 0; i < B; i++) { int c = ucnt[i]; if (pbase >= cum) bb = i; cum += c; }
    int kstart = 0;
    for (int i = 0; i < bb; i++) kstart += kcnt[i];
    int kend = kstart + kcnt[bb];

    float ux = unk[p * 3 + 0], uy = unk[p * 3 + 1], uz = unk[p * 3 + 2];

    int qlen = (kend - kstart) >> 2;            // uniform (4096/4 batches)
    int jbase = kstart + s * qlen;              // uniform per wave
    const float* kq = kn + (size_t)jbase * 3;   // uniform base -> s_load

    float d0 = INF, d1 = INF, d2 = INF;
    auto upd = [&](float e) {                    // 2 max + 3 min, no compares
        float m0 = fmaxf(e, d0);
        float m1 = fmaxf(e, d1);
        d0 = fminf(e, d0);
        d1 = fminf(m0, d1);
        d2 = fminf(m1, d2);
    };

    // ----------------- pass 1: top-3 values over own quarter -----------------
    for (int i = 0; i < qlen; i += 8) {
        float e[8];
#pragma unroll
        for (int c = 0; c < 8; c++) {
            float kx = kq[(i + c) * 3 + 0];     // uniform -> SGPR
            float ky = kq[(i + c) * 3 + 1];
            float kz = kq[(i + c) * 3 + 2];
            float dx = kx - ux, dy = ky - uy, dz = kz - uz;
            e[c] = __builtin_fmaf(dx, dx, __builtin_fmaf(dy, dy, dz * dz));
        }
#pragma unroll
        for (int c = 0; c < 8; c++) upd(e[c]);
    }

    md[s][lane][0] = d0; md[s][lane][1] = d1; md[s][lane][2] = d2;
    __syncthreads();
    if (tid < 64) {
        float v0 = INF, v1 = INF, v2 = INF;
#pragma unroll
        for (int w = 0; w < 4; w++)
#pragma unroll
            for (int k = 0; k < 3; k++) {
                float e = md[w][tid][k];
                float m0 = fmaxf(e, v0);
                float m1 = fmaxf(e, v1);
                v0 = fminf(e, v0);
                v1 = fminf(m0, v1);
                v2 = fminf(m1, v2);
            }
        d2g[tid] = v2;
    }
    __syncthreads();
    float thr = d2g[lane];

    // ----------------- pass 2: collect indices (8-wide screened) -------------
    unsigned long long s0 = ~0ULL, s1 = ~0ULL, s2 = ~0ULL;
    auto insK = [&](unsigned long long k) {
        bool c0 = k < s0;
        unsigned long long t0 = c0 ? k : s0;
        unsigned long long t1 = c0 ? s0 : k;
        bool c1 = t1 < s1;
        unsigned long long u0 = c1 ? t1 : s1;
        unsigned long long u1 = c1 ? s1 : t1;
        s0 = t0; s1 = u0;
        s2 = u1 < s2 ? u1 : s2;
    };
    auto mkkey = [](float e, int gj) {
        return ((unsigned long long)__float_as_uint(e) << 32) | (unsigned)gj;
    };

    for (int i = 0; i < qlen; i += 8) {
        float e[8];
#pragma unroll
        for (int c = 0; c < 8; c++) {
            float kx = kq[(i + c) * 3 + 0];
            float ky = kq[(i + c) * 3 + 1];
            float kz = kq[(i + c) * 3 + 2];
            float dx = kx - ux, dy = ky - uy, dz = kz - uz;
            e[c] = __builtin_fmaf(dx, dx, __builtin_fmaf(dy, dy, dz * dz));
        }
        float m8 = fminf(fminf(fminf(e[0], e[1]), fminf(e[2], e[3])),
                         fminf(fminf(e[4], e[5]), fminf(e[6], e[7])));
        if (m8 <= thr) {
            int gj = jbase + i;
#pragma unroll
            for (int c = 0; c < 8; c++) insK(mkkey(e[c], gj + c));
        }
    }

    mk[s][lane][0] = s0; mk[s][lane][1] = s1; mk[s][lane][2] = s2;
    __syncthreads();

    if (tid < 64) {
        s0 = s1 = s2 = ~0ULL;
#pragma unroll
        for (int qq = 0; qq < 4; qq++)
#pragma unroll
            for (int kk = 0; kk < 3; kk++)
                insK(mk[qq][tid][kk]);

        float dd0 = __uint_as_float((unsigned)(s0 >> 32));
        float dd1 = __uint_as_float((unsigned)(s1 >> 32));
        float dd2 = __uint_as_float((unsigned)(s2 >> 32));
        float r0 = 1.0f / (dd0 + 1e-8f);
        float r1 = 1.0f / (dd1 + 1e-8f);
        float r2 = 1.0f / (dd2 + 1e-8f);
        float rs = 1.0f / (r0 + r1 + r2);
        int pp = pbase + tid;
        wgt[pp * 3 + 0] = r0 * rs;
        wgt[pp * 3 + 1] = r1 * rs;
        wgt[pp * 3 + 2] = r2 * rs;
        idxo[pp * 3 + 0] = (int)(unsigned)s0;
        idxo[pp * 3 + 1] = (int)(unsigned)s1;
        idxo[pp * 3 + 2] = (int)(unsigned)s2;
    }
}

// ------------------------------------------------ weight fp32->bf16 conv --
__global__ __launch_bounds__(256) void wconv_kernel(
    const float* __restrict__ W1, const float* __restrict__ W2,
    unsigned short* __restrict__ W1b, unsigned short* __restrict__ W2b,
    int n1, int n2)
{
    int i = blockIdx.x * 256 + threadIdx.x;
    if (i < n1) W1b[i] = f2bf(W1[i]);
    int j = i - n1;
    if (j >= 0 && j < n2) W2b[j] = f2bf(W2[j]);
}

// -------------------------------------------------------- bf16 MFMA GEMM --
// C[N,256] = A[N,K] x W[256,K]^T.  128x128 tile, BK=32, 16x16x32 MFMA.
// MODE 2 (gemm1): A materialized on the fly in staging:
//   cols 0..255  = interp (gather 3 kfeat rows via wgt/idx, fma, bf16)
//   cols 256..383 = ufeat (fp32->bf16)
// MODE 1 (gemm2): A = relu(h1*scale+shift) bf16, scale/shift computed in a
//   256-thread LDS prologue from raw BN sums (bn_finalize folded in).
// Fused epilogue: per-block column sum/sumsq of C -> global atomics.
template <int K, int MODE>
__global__ __launch_bounds__(256) void gemm_bf16_kernel(
    const void* __restrict__ Aa, const float* __restrict__ ufeat,
    const unsigned short* __restrict__ W,
    const float* __restrict__ wgt, const int* __restrict__ idxv,
    const float* __restrict__ bnsum, const float* __restrict__ bnsq,
    const float* __restrict__ bng, const float* __restrict__ bnb, float invN,
    float* __restrict__ C, float* __restrict__ gsum, float* __restrict__ gsq)
{
    __shared__ unsigned short As[128 * 40];
    __shared__ unsigned short Bs[128 * 40];
    __shared__ float colsum[128];
    __shared__ float colsq[128];
    __shared__ float sc[256], sh[256];

    int tid = threadIdx.x;
    int w = tid >> 6, lane = tid & 63;
    int r = w >> 1, cq = w & 1;
    int m16 = lane & 15, q = lane >> 4;
    int bm = blockIdx.x * 128, bn = blockIdx.y * 128;

    if (MODE == 1) {            // fold bn_finalize: per-channel scale/shift
        float mean = bnsum[tid] * invN;
        float var = bnsq[tid] * invN - mean * mean;
        float scv = bng[tid] * rsqrtf(var + BN_EPS);
        sc[tid] = scv;
        sh[tid] = bnb[tid] - mean * scv;
    }

    // per-thread staging slots: rows r0, r0+64 with fixed 8-ch chunk kc
    int srow = tid >> 2;
    int kc = (tid & 3) * 8;
    float w0a[2], w1a[2], w2a[2];
    int j0a[2], j1a[2], j2a[2];
    if (MODE == 2) {
#pragma unroll
        for (int t = 0; t < 2; t++) {
            int pp = bm + srow + 64 * t;
            w0a[t] = wgt[pp * 3 + 0]; w1a[t] = wgt[pp * 3 + 1]; w2a[t] = wgt[pp * 3 + 2];
            j0a[t] = idxv[pp * 3 + 0]; j1a[t] = idxv[pp * 3 + 1]; j2a[t] = idxv[pp * 3 + 2];
        }
    }

    f32x4 acc[4][4];
#pragma unroll
    for (int i = 0; i < 4; i++)
#pragma unroll
        for (int j = 0; j < 4; j++) acc[i][j] = (f32x4){0.f, 0.f, 0.f, 0.f};

#pragma unroll
    for (int k0 = 0; k0 < K; k0 += 32) {
        __syncthreads();
#pragma unroll
        for (int t = 0; t < 2; t++) {
            int row = srow + 64 * t;
            int c = k0 + kc;
            if (MODE == 2) {
                ushort4 o0, o1;
                if (c < 256) {          // interp cols (compile-time per iter)
                    const float* f0 = (const float*)Aa + (size_t)j0a[t] * 256 + c;
                    const float* f1 = (const float*)Aa + (size_t)j1a[t] * 256 + c;
                    const float* f2 = (const float*)Aa + (size_t)j2a[t] * 256 + c;
                    float4 x0 = *(const float4*)f0, x1 = *(const float4*)(f0 + 4);
                    float4 y0 = *(const float4*)f1, y1 = *(const float4*)(f1 + 4);
                    float4 z0 = *(const float4*)f2, z1 = *(const float4*)(f2 + 4);
                    float W0 = w0a[t], W1 = w1a[t], W2 = w2a[t];
                    o0.x = f2bf(x0.x * W0 + y0.x * W1 + z0.x * W2);
                    o0.y = f2bf(x0.y * W0 + y0.y * W1 + z0.y * W2);
                    o0.z = f2bf(x0.z * W0 + y0.z * W1 + z0.z * W2);
                    o0.w = f2bf(x0.w * W0 + y0.w * W1 + z0.w * W2);
                    o1.x = f2bf(x1.x * W0 + y1.x * W1 + z1.x * W2);
                    o1.y = f2bf(x1.y * W0 + y1.y * W1 + z1.y * W2);
                    o1.z = f2bf(x1.z * W0 + y1.z * W1 + z1.z * W2);
                    o1.w = f2bf(x1.w * W0 + y1.w * W1 + z1.w * W2);
                } else {                // ufeat cols
                    const float* fu = ufeat + (size_t)(bm + row) * 128 + (c - 256);
                    float4 u0 = *(const float4*)fu, u1 = *(const float4*)(fu + 4);
                    o0.x = f2bf(u0.x); o0.y = f2bf(u0.y);
                    o0.z = f2bf(u0.z); o0.w = f2bf(u0.w);
                    o1.x = f2bf(u1.x); o1.y = f2bf(u1.y);
                    o1.z = f2bf(u1.z); o1.w = f2bf(u1.w);
                }
                *(ushort4*)&As[row * 40 + kc] = o0;
                *(ushort4*)&As[row * 40 + kc + 4] = o1;
            } else {                    // MODE 1: bn+relu+bf16 from fp32 h1
                const float* Af = (const float*)Aa;
                float4 v0 = *(const float4*)(Af + (size_t)(bm + row) * K + c);
                float4 v1 = *(const float4*)(Af + (size_t)(bm + row) * K + c + 4);
                float4 s0 = *(const float4*)&sc[c];
                float4 s1 = *(const float4*)&sc[c + 4];
                float4 t0 = *(const float4*)&sh[c];
                float4 t1 = *(const float4*)&sh[c + 4];
                ushort4 o0, o1;
                o0.x = f2bf(fmaxf(v0.x * s0.x + t0.x, 0.f));
                o0.y = f2bf(fmaxf(v0.y * s0.y + t0.y, 0.f));
                o0.z = f2bf(fmaxf(v0.z * s0.z + t0.z, 0.f));
                o0.w = f2bf(fmaxf(v0.w * s0.w + t0.w, 0.f));
                o1.x = f2bf(fmaxf(v1.x * s1.x + t1.x, 0.f));
                o1.y = f2bf(fmaxf(v1.y * s1.y + t1.y, 0.f));
                o1.z = f2bf(fmaxf(v1.z * s1.z + t1.z, 0.f));
                o1.w = f2bf(fmaxf(v1.w * s1.w + t1.w, 0.f));
                *(ushort4*)&As[row * 40 + kc] = o0;
                *(ushort4*)&As[row * 40 + kc + 4] = o1;
            }
            *(short8*)&Bs[row * 40 + kc] =
                *(const short8*)(W + (size_t)(bn + row) * K + k0 + kc);
        }
        __syncthreads();

        short8 af[4], bf[4];
#pragma unroll
        for (int sub = 0; sub < 4; sub++) {
            af[sub] = *(const short8*)&As[(r * 64 + sub * 16 + m16) * 40 + q * 8];
            bf[sub] = *(const short8*)&Bs[(cq * 64 + sub * 16 + m16) * 40 + q * 8];
        }
#pragma unroll
        for (int sm = 0; sm < 4; sm++)
#pragma unroll
            for (int sn = 0; sn < 4; sn++)
                acc[sm][sn] = __builtin_amdgcn_mfma_f32_16x16x32_bf16(
                    af[sm], bf[sn], acc[sm][sn], 0, 0, 0);
    }

    int row0 = bm + r * 64 + q * 4;
    int col0 = bn + cq * 64 + m16;
#pragma unroll
    for (int sm = 0; sm < 4; sm++)
#pragma unroll
        for (int sn = 0; sn < 4; sn++) {
            f32x4 v = acc[sm][sn];
#pragma unroll
            for (int reg = 0; reg < 4; reg++)
                C[(size_t)(row0 + sm * 16 + reg) * 256 + col0 + sn * 16] = v[reg];
        }

    // ---- fused BN stats: per-block column sums of the 128x128 C tile ----
    __syncthreads();
    if (tid < 128) { colsum[tid] = 0.f; colsq[tid] = 0.f; }
    __syncthreads();
#pragma unroll
    for (int sn = 0; sn < 4; sn++) {
        float sacc = 0.f, qacc = 0.f;
#pragma unroll
        for (int sm = 0; sm < 4; sm++) {
            f32x4 v = acc[sm][sn];
#pragma unroll
            for (int reg = 0; reg < 4; reg++) {
                sacc += v[reg];
                qacc += v[reg] * v[reg];
            }
        }
        int lc = cq * 64 + sn * 16 + m16;
        atomicAdd(&colsum[lc], sacc);
        atomicAdd(&colsq[lc], qacc);
    }
    __syncthreads();
    if (tid < 128) {
        atomicAdd(&gsum[bn + tid], colsum[tid]);
        atomicAdd(&gsq[bn + tid], colsq[tid]);
    }
}

// --------- final: h2(ws) -> bn(raw sums, folded finalize)+relu -> d_out ---
__global__ __launch_bounds__(256) void final_act_kernel(
    const float* __restrict__ h2, const float* __restrict__ bnsum,
    const float* __restrict__ bnsq, const float* __restrict__ bng,
    const float* __restrict__ bnb, float invN,
    float* __restrict__ out, int total4)
{
    __shared__ float sc[256], sh[256];
    int c = threadIdx.x;
    float mean = bnsum[c] * invN;
    float var = bnsq[c] * invN - mean * mean;
    float scv = bng[c] * rsqrtf(var + BN_EPS);
    sc[c] = scv;
    sh[c] = bnb[c] - mean * scv;
    __syncthreads();

    int i = blockIdx.x * 256 + threadIdx.x;
    if (i >= total4) return;
    int c4 = i & 63;
    float4 v = ((const float4*)h2)[i];
    float4 s = *(const float4*)&sc[c4 * 4];
    float4 t = *(const float4*)&sh[c4 * 4];
    float4 o;
    o.x = fmaxf(v.x * s.x + t.x, 0.0f);
    o.y = fmaxf(v.y * s.y + t.y, 0.0f);
    o.z = fmaxf(v.z * s.z + t.z, 0.0f);
    o.w = fmaxf(v.w * s.w + t.w, 0.0f);
    ((float4*)out)[i] = o;
}

// ------------------------------------------------------------------ launch --
extern "C" void kernel_launch(void* const* d_in, const int* in_sizes, int n_in,
                              void* d_out, int out_size, void* d_ws, size_t ws_size,
                              hipStream_t stream)
{
    const float* unknown = (const float*)d_in[0];
    const int*   ucnt    = (const int*)d_in[1];
    const float* known   = (const float*)d_in[2];
    const int*   kcnt    = (const int*)d_in[3];
    const float* ufeat   = (const float*)d_in[4];
    const float* kfeat   = (const float*)d_in[5];
    const float* W1      = (const float*)d_in[6];
    const float* g1      = (const float*)d_in[7];
    const float* b1      = (const float*)d_in[8];
    const float* W2      = (const float*)d_in[9];
    const float* g2      = (const float*)d_in[10];
    const float* b2      = (const float*)d_in[11];

    int N = in_sizes[0] / 3;        // 65536
    int B = in_sizes[1];            // 4

    char* ws = (char*)d_ws;
    size_t off = 0;
    float* wgt = (float*)(ws + off);            off += (size_t)N * 3 * 4;
    int*   idxb = (int*)(ws + off);             off += (size_t)N * 3 * 4;
    float* stats = (float*)(ws + off);          off += 4 * 256 * 4;
    float* sum1 = stats,        *sq1 = stats + 256;
    float* sum2 = stats + 512,  *sq2 = stats + 768;
    unsigned short* W1b = (unsigned short*)(ws + off);  off += 256 * 384 * 2;
    unsigned short* W2b = (unsigned short*)(ws + off);  off += 256 * 256 * 2;
    off = (off + 255) & ~(size_t)255;
    float* h2 = (float*)(ws + off);             // N*256 fp32 (67MB)
    float* h1 = (float*)d_out;                  // h1 lives in d_out

    float invN = 1.0f / (float)N;

    hipMemsetAsync(stats, 0, 4 * 256 * 4, stream);

    knn3_kernel<<<N / 64, 256, 0, stream>>>(unknown, known, ucnt, kcnt,
                                            B, N, wgt, idxb);
    wconv_kernel<<<(256 * 384 + 256 * 256 + 255) / 256, 256, 0, stream>>>(
        W1, W2, W1b, W2b, 256 * 384, 256 * 256);
    gemm_bf16_kernel<384, 2><<<dim3(N / 128, 2), 256, 0, stream>>>(
        kfeat, ufeat, W1b, wgt, idxb,
        nullptr, nullptr, nullptr, nullptr, 0.f, h1, sum1, sq1);
    gemm_bf16_kernel<256, 1><<<dim3(N / 128, 2), 256, 0, stream>>>(
        h1, nullptr, W2b, nullptr, nullptr,
        sum1, sq1, g1, b1, invN, h2, sum2, sq2);
    final_act_kernel<<<N / 4, 256, 0, stream>>>(h2, sum2, sq2, g2, b2, invN,
                                                (float*)d_out, N * 64);
}

// Round 10
// 388.583 us; speedup vs baseline: 1.0271x; 1.0271x over previous
//
#include <hip/hip_runtime.h>
#include <math.h>

typedef __attribute__((ext_vector_type(8))) short short8;
typedef __attribute__((ext_vector_type(4))) float f32x4;

#define INF 3.0e38f
#define BN_EPS 1e-5f

__device__ __forceinline__ unsigned short f2bf(float x) {
    union { float f; unsigned u; } v; v.f = x;
    unsigned r = v.u + 0x7FFF + ((v.u >> 16) & 1);   // RNE
    return (unsigned short)(r >> 16);
}
__device__ __forceinline__ float bf2f(unsigned short u) {
    return __uint_as_float(((unsigned)u) << 16);
}

// ---------------------------------------------------------------- 3-NN ----
// Scalar-pipe scan (SMEM loads, no LDS staging). Two-pass: pass 1 = top-3
// values (5-op min/max net); merge -> thr; pass 2 = rescan with 4-wide screen
// (wave-level P(hit)~0.59 -- 8-wide was worse: P(hit)~0.83, r9 regression),
// rare u64 (f32bits<<32|idx) lex insert. Selection == lax.top_k, bit-exact.
__global__ __launch_bounds__(256) void knn3_kernel(
    const float* __restrict__ unk, const float* __restrict__ kn,
    const int* __restrict__ ucnt, const int* __restrict__ kcnt,
    int B, int N, float* __restrict__ wgt, int* __restrict__ idxo)
{
    __shared__ float md[4][64][3];
    __shared__ float d2g[64];
    __shared__ unsigned long long mk[4][64][3];

    int tid = threadIdx.x;
    int s = __builtin_amdgcn_readfirstlane(tid >> 6);   // wave id, pinned SGPR
    int lane = tid & 63;
    int pbase = blockIdx.x * 64;
    int p = pbase + lane;

    int cum = 0, bb = 0;
    for (int i = 0; i < B; i++) { int c = ucnt[i]; if (pbase >= cum) bb = i; cum += c; }
    int kstart = 0;
    for (int i = 0; i < bb; i++) kstart += kcnt[i];
    int kend = kstart + kcnt[bb];

    float ux = unk[p * 3 + 0], uy = unk[p * 3 + 1], uz = unk[p * 3 + 2];

    int qlen = (kend - kstart) >> 2;            // uniform (4096/4 batches)
    int jbase = kstart + s * qlen;              // uniform per wave
    const float* kq = kn + (size_t)jbase * 3;   // uniform base -> s_load

    float d0 = INF, d1 = INF, d2 = INF;
    auto upd = [&](float e) {                    // 2 max + 3 min, no compares
        float m0 = fmaxf(e, d0);
        float m1 = fmaxf(e, d1);
        d0 = fminf(e, d0);
        d1 = fminf(m0, d1);
        d2 = fminf(m1, d2);
    };

    // ----------------- pass 1: top-3 values over own quarter -----------------
    for (int i = 0; i < qlen; i += 8) {
        float e[8];
#pragma unroll
        for (int c = 0; c < 8; c++) {
            float kx = kq[(i + c) * 3 + 0];     // uniform -> SGPR
            float ky = kq[(i + c) * 3 + 1];
            float kz = kq[(i + c) * 3 + 2];
            float dx = kx - ux, dy = ky - uy, dz = kz - uz;
            e[c] = __builtin_fmaf(dx, dx, __builtin_fmaf(dy, dy, dz * dz));
        }
#pragma unroll
        for (int c = 0; c < 8; c++) upd(e[c]);
    }

    md[s][lane][0] = d0; md[s][lane][1] = d1; md[s][lane][2] = d2;
    __syncthreads();
    if (tid < 64) {
        float v0 = INF, v1 = INF, v2 = INF;
#pragma unroll
        for (int w = 0; w < 4; w++)
#pragma unroll
            for (int k = 0; k < 3; k++) {
                float e = md[w][tid][k];
                float m0 = fmaxf(e, v0);
                float m1 = fmaxf(e, v1);
                v0 = fminf(e, v0);
                v1 = fminf(m0, v1);
                v2 = fminf(m1, v2);
            }
        d2g[tid] = v2;
    }
    __syncthreads();
    float thr = d2g[lane];

    // ----------------- pass 2: collect indices (4-wide screened) -------------
    unsigned long long s0 = ~0ULL, s1 = ~0ULL, s2 = ~0ULL;
    auto insK = [&](unsigned long long k) {
        bool c0 = k < s0;
        unsigned long long t0 = c0 ? k : s0;
        unsigned long long t1 = c0 ? s0 : k;
        bool c1 = t1 < s1;
        unsigned long long u0 = c1 ? t1 : s1;
        unsigned long long u1 = c1 ? s1 : t1;
        s0 = t0; s1 = u0;
        s2 = u1 < s2 ? u1 : s2;
    };
    auto mkkey = [](float e, int gj) {
        return ((unsigned long long)__float_as_uint(e) << 32) | (unsigned)gj;
    };

    for (int i = 0; i < qlen; i += 4) {
        float e[4];
#pragma unroll
        for (int c = 0; c < 4; c++) {
            float kx = kq[(i + c) * 3 + 0];
            float ky = kq[(i + c) * 3 + 1];
            float kz = kq[(i + c) * 3 + 2];
            float dx = kx - ux, dy = ky - uy, dz = kz - uz;
            e[c] = __builtin_fmaf(dx, dx, __builtin_fmaf(dy, dy, dz * dz));
        }
        float m4 = fminf(fminf(e[0], e[1]), fminf(e[2], e[3]));
        if (m4 <= thr) {
            int gj = jbase + i;
            insK(mkkey(e[0], gj + 0));
            insK(mkkey(e[1], gj + 1));
            insK(mkkey(e[2], gj + 2));
            insK(mkkey(e[3], gj + 3));
        }
    }

    mk[s][lane][0] = s0; mk[s][lane][1] = s1; mk[s][lane][2] = s2;
    __syncthreads();

    if (tid < 64) {
        s0 = s1 = s2 = ~0ULL;
#pragma unroll
        for (int qq = 0; qq < 4; qq++)
#pragma unroll
            for (int kk = 0; kk < 3; kk++)
                insK(mk[qq][tid][kk]);

        float dd0 = __uint_as_float((unsigned)(s0 >> 32));
        float dd1 = __uint_as_float((unsigned)(s1 >> 32));
        float dd2 = __uint_as_float((unsigned)(s2 >> 32));
        float r0 = 1.0f / (dd0 + 1e-8f);
        float r1 = 1.0f / (dd1 + 1e-8f);
        float r2 = 1.0f / (dd2 + 1e-8f);
        float rs = 1.0f / (r0 + r1 + r2);
        int pp = pbase + tid;
        wgt[pp * 3 + 0] = r0 * rs;
        wgt[pp * 3 + 1] = r1 * rs;
        wgt[pp * 3 + 2] = r2 * rs;
        idxo[pp * 3 + 0] = (int)(unsigned)s0;
        idxo[pp * 3 + 1] = (int)(unsigned)s1;
        idxo[pp * 3 + 2] = (int)(unsigned)s2;
    }
}

// ------------------------------------------------ weight fp32->bf16 conv --
__global__ __launch_bounds__(256) void wconv_kernel(
    const float* __restrict__ W1, const float* __restrict__ W2,
    unsigned short* __restrict__ W1b, unsigned short* __restrict__ W2b,
    int n1, int n2)
{
    int i = blockIdx.x * 256 + threadIdx.x;
    if (i < n1) W1b[i] = f2bf(W1[i]);
    int j = i - n1;
    if (j >= 0 && j < n2) W2b[j] = f2bf(W2[j]);
}

// -------------------------------------------------------- bf16 MFMA GEMM --
// C[N,256] = A[N,K] x W[256,K]^T.  128x128 tile, BK=32, 16x16x32 MFMA.
// MODE 2 (gemm1): A materialized on the fly in staging (interp cols 0..255
//   gathered from kfeat via wgt/idx; ufeat cols 256..383). C stored as BF16
//   (h1) — BN1 stats come from fp32 accumulators, exact.
// MODE 1 (gemm2): A = relu(h1_bf16*scale+shift) -> bf16; scale/shift computed
//   in a 256-thread LDS prologue from raw BN sums (bn_finalize folded in).
//   C stored fp32 (h2).
// Fused epilogue: per-block column sum/sumsq of C -> global atomics.
template <int K, int MODE>
__global__ __launch_bounds__(256) void gemm_bf16_kernel(
    const void* __restrict__ Aa, const float* __restrict__ ufeat,
    const unsigned short* __restrict__ W,
    const float* __restrict__ wgt, const int* __restrict__ idxv,
    const float* __restrict__ bnsum, const float* __restrict__ bnsq,
    const float* __restrict__ bng, const float* __restrict__ bnb, float invN,
    void* __restrict__ Cv, float* __restrict__ gsum, float* __restrict__ gsq)
{
    __shared__ unsigned short As[128 * 40];
    __shared__ unsigned short Bs[128 * 40];
    __shared__ float colsum[128];
    __shared__ float colsq[128];
    __shared__ float sc[256], sh[256];

    int tid = threadIdx.x;
    int w = tid >> 6, lane = tid & 63;
    int r = w >> 1, cq = w & 1;
    int m16 = lane & 15, q = lane >> 4;
    int bm = blockIdx.x * 128, bn = blockIdx.y * 128;

    if (MODE == 1) {            // fold bn_finalize: per-channel scale/shift
        float mean = bnsum[tid] * invN;
        float var = bnsq[tid] * invN - mean * mean;
        float scv = bng[tid] * rsqrtf(var + BN_EPS);
        sc[tid] = scv;
        sh[tid] = bnb[tid] - mean * scv;
    }

    // per-thread staging slots: rows srow, srow+64 with fixed 8-ch chunk kc
    int srow = tid >> 2;
    int kc = (tid & 3) * 8;
    float w0a[2], w1a[2], w2a[2];
    int j0a[2], j1a[2], j2a[2];
    if (MODE == 2) {
#pragma unroll
        for (int t = 0; t < 2; t++) {
            int pp = bm + srow + 64 * t;
            w0a[t] = wgt[pp * 3 + 0]; w1a[t] = wgt[pp * 3 + 1]; w2a[t] = wgt[pp * 3 + 2];
            j0a[t] = idxv[pp * 3 + 0]; j1a[t] = idxv[pp * 3 + 1]; j2a[t] = idxv[pp * 3 + 2];
        }
    }

    f32x4 acc[4][4];
#pragma unroll
    for (int i = 0; i < 4; i++)
#pragma unroll
        for (int j = 0; j < 4; j++) acc[i][j] = (f32x4){0.f, 0.f, 0.f, 0.f};

#pragma unroll
    for (int k0 = 0; k0 < K; k0 += 32) {
        __syncthreads();
#pragma unroll
        for (int t = 0; t < 2; t++) {
            int row = srow + 64 * t;
            int c = k0 + kc;
            ushort4 o0, o1;
            if (MODE == 2) {
                if (c < 256) {          // interp cols (compile-time per iter)
                    const float* f0 = (const float*)Aa + (size_t)j0a[t] * 256 + c;
                    const float* f1 = (const float*)Aa + (size_t)j1a[t] * 256 + c;
                    const float* f2 = (const float*)Aa + (size_t)j2a[t] * 256 + c;
                    float4 x0 = *(const float4*)f0, x1 = *(const float4*)(f0 + 4);
                    float4 y0 = *(const float4*)f1, y1 = *(const float4*)(f1 + 4);
                    float4 z0 = *(const float4*)f2, z1 = *(const float4*)(f2 + 4);
                    float W0 = w0a[t], W1 = w1a[t], W2 = w2a[t];
                    o0.x = f2bf(x0.x * W0 + y0.x * W1 + z0.x * W2);
                    o0.y = f2bf(x0.y * W0 + y0.y * W1 + z0.y * W2);
                    o0.z = f2bf(x0.z * W0 + y0.z * W1 + z0.z * W2);
                    o0.w = f2bf(x0.w * W0 + y0.w * W1 + z0.w * W2);
                    o1.x = f2bf(x1.x * W0 + y1.x * W1 + z1.x * W2);
                    o1.y = f2bf(x1.y * W0 + y1.y * W1 + z1.y * W2);
                    o1.z = f2bf(x1.z * W0 + y1.z * W1 + z1.z * W2);
                    o1.w = f2bf(x1.w * W0 + y1.w * W1 + z1.w * W2);
                } else {                // ufeat cols
                    const float* fu = ufeat + (size_t)(bm + row) * 128 + (c - 256);
                    float4 u0 = *(const float4*)fu, u1 = *(const float4*)(fu + 4);
                    o0.x = f2bf(u0.x); o0.y = f2bf(u0.y);
                    o0.z = f2bf(u0.z); o0.w = f2bf(u0.w);
                    o1.x = f2bf(u1.x); o1.y = f2bf(u1.y);
                    o1.z = f2bf(u1.z); o1.w = f2bf(u1.w);
                }
            } else {                    // MODE 1: bn+relu+bf16 from bf16 h1
                const unsigned short* Ab = (const unsigned short*)Aa;
                ushort4 h0 = *(const ushort4*)(Ab + (size_t)(bm + row) * K + c);
                ushort4 h1v = *(const ushort4*)(Ab + (size_t)(bm + row) * K + c + 4);
                float4 s0 = *(const float4*)&sc[c];
                float4 s1 = *(const float4*)&sc[c + 4];
                float4 t0 = *(const float4*)&sh[c];
                float4 t1 = *(const float4*)&sh[c + 4];
                o0.x = f2bf(fmaxf(bf2f(h0.x) * s0.x + t0.x, 0.f));
                o0.y = f2bf(fmaxf(bf2f(h0.y) * s0.y + t0.y, 0.f));
                o0.z = f2bf(fmaxf(bf2f(h0.z) * s0.z + t0.z, 0.f));
                o0.w = f2bf(fmaxf(bf2f(h0.w) * s0.w + t0.w, 0.f));
                o1.x = f2bf(fmaxf(bf2f(h1v.x) * s1.x + t1.x, 0.f));
                o1.y = f2bf(fmaxf(bf2f(h1v.y) * s1.y + t1.y, 0.f));
                o1.z = f2bf(fmaxf(bf2f(h1v.z) * s1.z + t1.z, 0.f));
                o1.w = f2bf(fmaxf(bf2f(h1v.w) * s1.w + t1.w, 0.f));
            }
            *(ushort4*)&As[row * 40 + kc] = o0;
            *(ushort4*)&As[row * 40 + kc + 4] = o1;
            *(short8*)&Bs[row * 40 + kc] =
                *(const short8*)(W + (size_t)(bn + row) * K + k0 + kc);
        }
        __syncthreads();

        short8 af[4], bf[4];
#pragma unroll
        for (int sub = 0; sub < 4; sub++) {
            af[sub] = *(const short8*)&As[(r * 64 + sub * 16 + m16) * 40 + q * 8];
            bf[sub] = *(const short8*)&Bs[(cq * 64 + sub * 16 + m16) * 40 + q * 8];
        }
#pragma unroll
        for (int sm = 0; sm < 4; sm++)
#pragma unroll
            for (int sn = 0; sn < 4; sn++)
                acc[sm][sn] = __builtin_amdgcn_mfma_f32_16x16x32_bf16(
                    af[sm], bf[sn], acc[sm][sn], 0, 0, 0);
    }

    int row0 = bm + r * 64 + q * 4;
    int col0 = bn + cq * 64 + m16;
#pragma unroll
    for (int sm = 0; sm < 4; sm++)
#pragma unroll
        for (int sn = 0; sn < 4; sn++) {
            f32x4 v = acc[sm][sn];
#pragma unroll
            for (int reg = 0; reg < 4; reg++) {
                size_t idx = (size_t)(row0 + sm * 16 + reg) * 256 + col0 + sn * 16;
                if (MODE == 2) ((unsigned short*)Cv)[idx] = f2bf(v[reg]);
                else           ((float*)Cv)[idx] = v[reg];
            }
        }

    // ---- fused BN stats: per-block column sums of the 128x128 C tile ----
    __syncthreads();
    if (tid < 128) { colsum[tid] = 0.f; colsq[tid] = 0.f; }
    __syncthreads();
#pragma unroll
    for (int sn = 0; sn < 4; sn++) {
        float sacc = 0.f, qacc = 0.f;
#pragma unroll
        for (int sm = 0; sm < 4; sm++) {
            f32x4 v = acc[sm][sn];
#pragma unroll
            for (int reg = 0; reg < 4; reg++) {
                sacc += v[reg];
                qacc += v[reg] * v[reg];
            }
        }
        int lc = cq * 64 + sn * 16 + m16;
        atomicAdd(&colsum[lc], sacc);
        atomicAdd(&colsq[lc], qacc);
    }
    __syncthreads();
    if (tid < 128) {
        atomicAdd(&gsum[bn + tid], colsum[tid]);
        atomicAdd(&gsq[bn + tid], colsq[tid]);
    }
}

// --------- final: h2(ws) -> bn(raw sums, folded finalize)+relu -> d_out ---
__global__ __launch_bounds__(256) void final_act_kernel(
    const float* __restrict__ h2, const float* __restrict__ bnsum,
    const float* __restrict__ bnsq, const float* __restrict__ bng,
    const float* __restrict__ bnb, float invN,
    float* __restrict__ out, int total4)
{
    __shared__ float sc[256], sh[256];
    int c = threadIdx.x;
    float mean = bnsum[c] * invN;
    float var = bnsq[c] * invN - mean * mean;
    float scv = bng[c] * rsqrtf(var + BN_EPS);
    sc[c] = scv;
    sh[c] = bnb[c] - mean * scv;
    __syncthreads();

    int i = blockIdx.x * 256 + threadIdx.x;
    if (i >= total4) return;
    int c4 = i & 63;
    float4 v = ((const float4*)h2)[i];
    float4 s = *(const float4*)&sc[c4 * 4];
    float4 t = *(const float4*)&sh[c4 * 4];
    float4 o;
    o.x = fmaxf(v.x * s.x + t.x, 0.0f);
    o.y = fmaxf(v.y * s.y + t.y, 0.0f);
    o.z = fmaxf(v.z * s.z + t.z, 0.0f);
    o.w = fmaxf(v.w * s.w + t.w, 0.0f);
    ((float4*)out)[i] = o;
}

// ------------------------------------------------------------------ launch --
extern "C" void kernel_launch(void* const* d_in, const int* in_sizes, int n_in,
                              void* d_out, int out_size, void* d_ws, size_t ws_size,
                              hipStream_t stream)
{
    const float* unknown = (const float*)d_in[0];
    const int*   ucnt    = (const int*)d_in[1];
    const float* known   = (const float*)d_in[2];
    const int*   kcnt    = (const int*)d_in[3];
    const float* ufeat   = (const float*)d_in[4];
    const float* kfeat   = (const float*)d_in[5];
    const float* W1      = (const float*)d_in[6];
    const float* g1      = (const float*)d_in[7];
    const float* b1      = (const float*)d_in[8];
    const float* W2      = (const float*)d_in[9];
    const float* g2      = (const float*)d_in[10];
    const float* b2      = (const float*)d_in[11];

    int N = in_sizes[0] / 3;        // 65536
    int B = in_sizes[1];            // 4

    char* ws = (char*)d_ws;
    size_t off = 0;
    float* wgt = (float*)(ws + off);            off += (size_t)N * 3 * 4;
    int*   idxb = (int*)(ws + off);             off += (size_t)N * 3 * 4;
    float* stats = (float*)(ws + off);          off += 4 * 256 * 4;
    float* sum1 = stats,        *sq1 = stats + 256;
    float* sum2 = stats + 512,  *sq2 = stats + 768;
    unsigned short* W1b = (unsigned short*)(ws + off);  off += 256 * 384 * 2;
    unsigned short* W2b = (unsigned short*)(ws + off);  off += 256 * 256 * 2;
    off = (off + 255) & ~(size_t)255;
    unsigned short* h1 = (unsigned short*)(ws + off);   off += (size_t)N * 256 * 2;
    off = (off + 255) & ~(size_t)255;
    float* h2 = (float*)(ws + off);             // N*256 fp32 (67MB)

    float invN = 1.0f / (float)N;

    hipMemsetAsync(stats, 0, 4 * 256 * 4, stream);

    wconv_kernel<<<(256 * 384 + 256 * 256 + 255) / 256, 256, 0, stream>>>(
        W1, W2, W1b, W2b, 256 * 384, 256 * 256);
    knn3_kernel<<<N / 64, 256, 0, stream>>>(unknown, known, ucnt, kcnt,
                                            B, N, wgt, idxb);
    gemm_bf16_kernel<384, 2><<<dim3(N / 128, 2), 256, 0, stream>>>(
        kfeat, ufeat, W1b, wgt, idxb,
        nullptr, nullptr, nullptr, nullptr, 0.f, h1, sum1, sq1);
    gemm_bf16_kernel<256, 1><<<dim3(N / 128, 2), 256, 0, stream>>>(
        h1, nullptr, W2b, nullptr, nullptr,
        sum1, sq1, g1, b1, invN, h2, sum2, sq2);
    final_act_kernel<<<N / 4, 256, 0, stream>>>(h2, sum2, sq2, g2, b2, invN,
                                                (float*)d_out, N * 64);
}